// Round 10
// baseline (147.580 us; speedup 1.0000x reference)
//
#include <hip/hip_runtime.h>
#include <hip/hip_bf16.h>
#include <stdint.h>

// VectorQuantizer: z_e (64,64,64,64) fp32, codebook (512,64) fp32.
// out = [z_q 16777216 floats][codebook_loss][commitment_loss]
//
// v14 = v9 (best fused, 42.2us) + 3 ablation PROBES (write only to ws).
// v13 post-mortem: split showed dequant 11us@5-6TB/s but argmin ALONE = 41.6
// = full fused time (output writes were free all along). dur_us arithmetic:
// ~84us of every run is two fixed 256MB harness poison fills; controllable
// part is ~44us, entirely the argmin phase. 8 structural variants pin at
// 42+-3us with all pipes >=80% idle -- no counter-derivable theory survived
// (occupancy/prefetch/stores/fp8/dense-grain/duty-cycle all falsified).
// Per skill: ablate empirically. Probes isolate (E) dispatch cost,
// (L) the exact P1 scattered-load pattern, (M) the exact P2/P3 MFMA+argmax
// pipeline on synthetic inputs. Whichever reads ~40us is the stall; if L,M
// are each ~20 and sum to 42, phases just concatenate (no cross-block
// overlap) and R10 attacks that with evidence. Probes cost dur_us this
// round by design. Main path = v9 verbatim: bf16 cb in XOR-swizzled 64KB
// LDS, 2 slabs/block, dot-argmax bit-trick, ks-transposed plane-contiguous
// P4', loss block-reduce + 2 scaled atomicAdds.

typedef __bf16 bf16x8 __attribute__((ext_vector_type(8)));
typedef float f32x16 __attribute__((ext_vector_type(16)));

union ABu { uint32_t w[4]; uint4 u4; bf16x8 v; };

__device__ inline uint32_t pack_bf16(float a, float b) {
  __hip_bfloat162 h = __float22bfloat162_rn(make_float2(a, b));
  uint32_t u;
  __builtin_memcpy(&u, &h, 4);
  return u;
}

// ---- prep: codebook fp32 -> bf16 (packed u32) + e2[k]
__global__ __launch_bounds__(256)
void vq_prep(const float* __restrict__ cb, uint32_t* __restrict__ cb_bf,
             float* __restrict__ e2) {
  int t = blockIdx.x * 256 + threadIdx.x;  // 0..16383, one u32 of cb_bf
  float2 f = ((const float2*)cb)[t];
  uint32_t u = pack_bf16(f.x, f.y);
  cb_bf[t] = u;
  __hip_bfloat162 h;
  __builtin_memcpy(&h, &u, 4);
  float2 fb = __bfloat1622float2(h);
  float s = fb.x * fb.x + fb.y * fb.y;
#pragma unroll
  for (int off = 1; off <= 16; off <<= 1) s += __shfl_xor(s, off);
  if ((t & 31) == 0) e2[t >> 5] = s;  // code = t>>5
}

// ---- main: 512 blocks x 256 threads (v9 verbatim)
__global__ __launch_bounds__(256)
void vq_main(const float* __restrict__ zin, const uint32_t* __restrict__ cb_bf,
             const float* __restrict__ e2g, float* __restrict__ out) {
  __shared__ uint32_t cbl[16384];  // exactly 64 KB
  __shared__ unsigned short ks[2][256] __attribute__((aligned(16)));
  const int tid = threadIdx.x;
  const int wid = tid >> 6;
  const int lane = tid & 63;
  const int col = lane & 31;
  const int half = lane >> 5;
  const int xk = col & 7;

  {
    const uint4* cb4 = (const uint4*)cb_bf;
#pragma unroll
    for (int j = 0; j < 16; ++j) {
      int g = j * 256 + tid;
      int k = g >> 3, c = g & 7;
      *(uint4*)&cbl[k * 32 + ((c ^ (k & 7)) << 2)] = cb4[g];
    }
  }
  __syncthreads();

  float blk = 0.f;

#pragma unroll 1
  for (int it = 0; it < 2; ++it) {
    const int s = blockIdx.x * 2 + it;
    const int b = s >> 4;
    const int hw0 = (s & 15) << 8;
    const float* slab = zin + ((size_t)b << 18) + hw0;

    ABu Bf[2][4];
    float z2[2];
#pragma unroll
    for (int rt = 0; rt < 2; ++rt) {
      const int r = wid * 64 + rt * 32 + col;
      float sacc = 0.f;
#pragma unroll
      for (int m = 0; m < 4; ++m) {
        const int d0 = m * 16 + half * 8;
#pragma unroll
        for (int p = 0; p < 4; ++p) {
          float va = slab[(size_t)(d0 + 2 * p) * 4096 + r];
          float vb = slab[(size_t)(d0 + 2 * p + 1) * 4096 + r];
          sacc += va * va + vb * vb;
          Bf[rt][m].w[p] = pack_bf16(va, vb);
        }
      }
      z2[rt] = sacc;
    }

    ABu A[4], An[4];
#pragma unroll
    for (int m = 0; m < 4; ++m)
      A[m].u4 = *(const uint4*)&cbl[(col << 5) + (((2 * m + half) ^ xk) << 2)];
    float st[2] = {-3.4e38f, -3.4e38f};
#pragma unroll 1
    for (int ct = 0; ct < 16; ++ct) {
      const int ctn = (ct + 1) & 15;
      const int nbase = (ctn << 10) + (col << 5);
#pragma unroll
      for (int m = 0; m < 4; ++m)
        An[m].u4 = *(const uint4*)&cbl[nbase + (((2 * m + half) ^ xk) << 2)];
      const uint32_t ctor = (uint32_t)(ct << 5) | (uint32_t)(half << 2);
#pragma unroll
      for (int rt = 0; rt < 2; ++rt) {
        f32x16 acc = {0, 0, 0, 0, 0, 0, 0, 0, 0, 0, 0, 0, 0, 0, 0, 0};
#pragma unroll
        for (int m = 0; m < 4; ++m)
          acc = __builtin_amdgcn_mfma_f32_32x32x16_bf16(A[m].v, Bf[rt][m].v, acc, 0, 0, 0);
#pragma unroll
        for (int r16 = 0; r16 < 16; ++r16) {
          const uint32_t cr = (uint32_t)((r16 & 3) | ((r16 >> 2) << 3));
          uint32_t bits =
              (__builtin_bit_cast(uint32_t, acc[r16]) & 0xFFFFFE00u) | (ctor | cr);
          st[rt] = fmaxf(st[rt], __builtin_bit_cast(float, bits));
        }
      }
#pragma unroll
      for (int m = 0; m < 4; ++m) A[m].u4 = An[m].u4;
    }

    {
      float lsum = 0.f;
      int kk[2];
#pragma unroll
      for (int rt = 0; rt < 2; ++rt) {
        float mx = fmaxf(st[rt], __shfl_xor(st[rt], 32));
        float z2t = z2[rt] + __shfl_xor(z2[rt], 32);
        uint32_t mbits = __builtin_bit_cast(uint32_t, mx);
        kk[rt] = (int)(mbits & 511u);
        float dot = __builtin_bit_cast(float, mbits & 0xFFFFFE00u);
        lsum += z2t - 2.f * dot + e2g[kk[rt]];
      }
#pragma unroll
      for (int off = 1; off <= 16; off <<= 1) lsum += __shfl_xor(lsum, off);
      blk += lsum;
      if (half == 0) {
        ks[it][wid * 64 + col] = (unsigned short)kk[0];
        ks[it][wid * 64 + 32 + col] = (unsigned short)kk[1];
      }
    }
    __syncthreads();

    {
      float* oslab = out + ((size_t)b << 18) + hw0;
      const int r0 = (lane << 2);
      const uint2 kp = *(const uint2*)&ks[it][r0];
      int k4[4];
      k4[0] = (int)(kp.x & 0xFFFFu);
      k4[1] = (int)(kp.x >> 16);
      k4[2] = (int)(kp.y & 0xFFFFu);
      k4[3] = (int)(kp.y >> 16);
#pragma unroll
      for (int i = 0; i < 8; ++i) {
        const int d = wid * 16 + i * 2;
        const int c = (wid << 1) + (i >> 2);
        const int jj = i & 3;
        uint32_t wv[4];
#pragma unroll
        for (int j = 0; j < 4; ++j)
          wv[j] = cbl[(k4[j] << 5) + (((c ^ (k4[j] & 7)) << 2) + jj)];
        float4 lo, hi;
        lo.x = __builtin_bit_cast(float, wv[0] << 16);
        lo.y = __builtin_bit_cast(float, wv[1] << 16);
        lo.z = __builtin_bit_cast(float, wv[2] << 16);
        lo.w = __builtin_bit_cast(float, wv[3] << 16);
        hi.x = __builtin_bit_cast(float, wv[0] & 0xFFFF0000u);
        hi.y = __builtin_bit_cast(float, wv[1] & 0xFFFF0000u);
        hi.z = __builtin_bit_cast(float, wv[2] & 0xFFFF0000u);
        hi.w = __builtin_bit_cast(float, wv[3] & 0xFFFF0000u);
        *(float4*)&oslab[(size_t)d * 4096 + r0] = lo;
        *(float4*)&oslab[(size_t)(d + 1) * 4096 + r0] = hi;
      }
    }
  }

  __syncthreads();
  if (lane == 0) ((float*)cbl)[wid] = blk;
  __syncthreads();
  if (tid == 0) {
    float t = ((float*)cbl)[0] + ((float*)cbl)[1] + ((float*)cbl)[2] + ((float*)cbl)[3];
    float sc = t * (1.0f / 16777216.0f);
    atomicAdd(out + 16777216, sc);
    atomicAdd(out + 16777217, 0.25f * sc);
  }
}

// ==== PROBES: isolate the 42us stall. Write only to ws scratch. ====

// E: dispatch/launch cost only.
__global__ __launch_bounds__(256)
void probe_empty(float* __restrict__ pout) {
  pout[(size_t)blockIdx.x * 256 + threadIdx.x] = (float)threadIdx.x;
}

// L: EXACT v9 P1 load pattern over the full input; minimal compute.
__global__ __launch_bounds__(256)
void probe_loads(const float* __restrict__ zin, float* __restrict__ pout) {
  const int tid = threadIdx.x;
  const int wid = tid >> 6;
  const int lane = tid & 63;
  const int col = lane & 31;
  const int half = lane >> 5;
  const int s = blockIdx.x;  // 1024 slabs of 256 rows = full input
  const int b = s >> 4;
  const int hw0 = (s & 15) << 8;
  const float* slab = zin + ((size_t)b << 18) + hw0;
  float acc = 0.f;
  uint32_t chk = 0;
#pragma unroll
  for (int rt = 0; rt < 2; ++rt) {
    const int r = wid * 64 + rt * 32 + col;
#pragma unroll
    for (int m = 0; m < 4; ++m) {
      const int d0 = m * 16 + half * 8;
#pragma unroll
      for (int p = 0; p < 4; ++p) {
        float va = slab[(size_t)(d0 + 2 * p) * 4096 + r];
        float vb = slab[(size_t)(d0 + 2 * p + 1) * 4096 + r];
        acc += va * va + vb * vb;
        chk ^= pack_bf16(va, vb);
      }
    }
  }
  pout[(size_t)s * 256 + tid] = acc + (float)(chk & 0xFFu);
}

// M: LDS fill + EXACT P2/P3 MFMA+argmax pipeline on synthetic B-frags.
__global__ __launch_bounds__(256)
void probe_mfma(const uint32_t* __restrict__ cb_bf, float* __restrict__ pout) {
  __shared__ uint32_t cbl[16384];  // 64 KB, same residency as vq_main
  const int tid = threadIdx.x;
  const int lane = tid & 63;
  const int col = lane & 31;
  const int half = lane >> 5;
  const int xk = col & 7;
  {
    const uint4* cb4 = (const uint4*)cb_bf;
#pragma unroll
    for (int j = 0; j < 16; ++j) {
      int g = j * 256 + tid;
      int k = g >> 3, c = g & 7;
      *(uint4*)&cbl[k * 32 + ((c ^ (k & 7)) << 2)] = cb4[g];
    }
  }
  __syncthreads();

  // synthetic, benign B-frags (no global z reads)
  ABu Bf[2][4];
#pragma unroll
  for (int rt = 0; rt < 2; ++rt)
#pragma unroll
    for (int m = 0; m < 4; ++m)
#pragma unroll
      for (int p = 0; p < 4; ++p)
        Bf[rt][m].w[p] = pack_bf16((float)((tid + p) & 31) * 0.01f,
                                   (float)((tid + m + p) & 31) * 0.007f);

  ABu A[4], An[4];
#pragma unroll
  for (int m = 0; m < 4; ++m)
    A[m].u4 = *(const uint4*)&cbl[(col << 5) + (((2 * m + half) ^ xk) << 2)];
  float st[2] = {-3.4e38f, -3.4e38f};
#pragma unroll 1
  for (int ct = 0; ct < 16; ++ct) {
    const int ctn = (ct + 1) & 15;
    const int nbase = (ctn << 10) + (col << 5);
#pragma unroll
    for (int m = 0; m < 4; ++m)
      An[m].u4 = *(const uint4*)&cbl[nbase + (((2 * m + half) ^ xk) << 2)];
    const uint32_t ctor = (uint32_t)(ct << 5) | (uint32_t)(half << 2);
#pragma unroll
    for (int rt = 0; rt < 2; ++rt) {
      f32x16 acc = {0, 0, 0, 0, 0, 0, 0, 0, 0, 0, 0, 0, 0, 0, 0, 0};
#pragma unroll
      for (int m = 0; m < 4; ++m)
        acc = __builtin_amdgcn_mfma_f32_32x32x16_bf16(A[m].v, Bf[rt][m].v, acc, 0, 0, 0);
#pragma unroll
      for (int r16 = 0; r16 < 16; ++r16) {
        const uint32_t cr = (uint32_t)((r16 & 3) | ((r16 >> 2) << 3));
        uint32_t bits =
            (__builtin_bit_cast(uint32_t, acc[r16]) & 0xFFFFFE00u) | (ctor | cr);
        st[rt] = fmaxf(st[rt], __builtin_bit_cast(float, bits));
      }
    }
#pragma unroll
    for (int m = 0; m < 4; ++m) A[m].u4 = An[m].u4;
  }
  float r = 0.f;
#pragma unroll
  for (int rt = 0; rt < 2; ++rt) {
    float mx = fmaxf(st[rt], __shfl_xor(st[rt], 32));
    r += (float)(__builtin_bit_cast(uint32_t, mx) & 511u);
  }
  pout[(size_t)blockIdx.x * 256 + tid] = r;
}

extern "C" void kernel_launch(void* const* d_in, const int* in_sizes, int n_in,
                              void* d_out, int out_size, void* d_ws, size_t ws_size,
                              hipStream_t stream) {
  const float* zin = (const float*)d_in[0];
  const float* cbf = (const float*)d_in[1];
  uint32_t* cb_bf = (uint32_t*)d_ws;                 // 64 KB bf16 codebook
  float* e2 = (float*)((char*)d_ws + 65536);         // 2 KB
  float* out = (float*)d_out;

  vq_prep<<<64, 256, 0, stream>>>(cbf, cb_bf, e2);
  vq_main<<<512, 256, 0, stream>>>(zin, cb_bf, e2, out);

  // ablation probes (scratch-only writes); gated on workspace size
  if (ws_size >= (16u << 20)) {
    float* p0 = (float*)((char*)d_ws + (4u << 20));
    float* p1 = (float*)((char*)d_ws + (8u << 20));
    float* p2 = (float*)((char*)d_ws + (12u << 20));
    probe_empty<<<1024, 256, 0, stream>>>(p0);
    probe_loads<<<1024, 256, 0, stream>>>(zin, p1);
    probe_mfma<<<512, 256, 0, stream>>>(cb_bf, p2);
  }
}

// Round 11
// 126.929 us; speedup vs baseline: 1.1627x; 1.1627x over previous
//
#include <hip/hip_runtime.h>
#include <hip/hip_bf16.h>
#include <stdint.h>

// VectorQuantizer: z_e (64,64,64,64) fp32, codebook (512,64) fp32.
// out = [z_q 16777216 floats][codebook_loss][commitment_loss]
//
// v15 = v9 + ONE change: software-pipelined P2 (argmax(ct-1) overlaps
// MFMA(ct) via ping-pong accumulators). v14 probe post-mortem: isolated
// phases sum to ~30us (loads ~11, mfma ~4-8, stores ~11, dispatch ~3) but
// fused P1+P2 alone = 41.6us -- the cost is per-wave dependency-chain
// serialization: per ct, 4-deep dependent MFMA chain -> 16-deep dependent
// fmax argmax reading the chain result -> next chain. In-order wave issue
// makes this a latency ladder (~3K cyc/ct vs ~400 issue cyc), x16 ct x2
// slabs with only 2 waves/SIMD to cover. Fix: ping-pong acc pairs (a0/a1,
// b0/b1 -- named vars, static indexing) so argmax VALU of the previous ct
// runs while the matrix pipe processes the current ct; rt0/rt1 chains
// interleaved per-m for 2x chain ILP. VGPR +64 (~160-200) is free: LDS
// (64KB) caps at 8 waves/CU, VGPR<=256 keeps 8. Probes removed.
// Kept from v9: bf16 cb in XOR-swizzled 64KB LDS, 2 slabs/block, 64-scalar
// P1, dot-argmax bit-trick, ks-transposed plane-contiguous P4', loss
// block-reduce + 2 scaled atomicAdds, plain __launch_bounds__(256).

typedef __bf16 bf16x8 __attribute__((ext_vector_type(8)));
typedef float f32x16 __attribute__((ext_vector_type(16)));

union ABu { uint32_t w[4]; uint4 u4; bf16x8 v; };

__device__ inline uint32_t pack_bf16(float a, float b) {
  __hip_bfloat162 h = __float22bfloat162_rn(make_float2(a, b));
  uint32_t u;
  __builtin_memcpy(&u, &h, 4);
  return u;
}

// ---- prep: codebook fp32 -> bf16 (packed u32) + e2[k]
__global__ __launch_bounds__(256)
void vq_prep(const float* __restrict__ cb, uint32_t* __restrict__ cb_bf,
             float* __restrict__ e2) {
  int t = blockIdx.x * 256 + threadIdx.x;  // 0..16383, one u32 of cb_bf
  float2 f = ((const float2*)cb)[t];
  uint32_t u = pack_bf16(f.x, f.y);
  cb_bf[t] = u;
  __hip_bfloat162 h;
  __builtin_memcpy(&h, &u, 4);
  float2 fb = __bfloat1622float2(h);
  float s = fb.x * fb.x + fb.y * fb.y;
#pragma unroll
  for (int off = 1; off <= 16; off <<= 1) s += __shfl_xor(s, off);
  if ((t & 31) == 0) e2[t >> 5] = s;  // code = t>>5
}

// P2 pipeline macros (static names only; rule #20: no runtime-indexed accs)
#define VQ_LOAD_AN(CTN)                                                     \
  {                                                                         \
    const int nbase = ((CTN) << 10) + (col << 5);                           \
    _Pragma("unroll") for (int m = 0; m < 4; ++m)                           \
        An[m].u4 = *(const uint4*)&cbl[nbase + (((2 * m + half) ^ xk) << 2)]; \
  }

#define VQ_MFMA(P0, P1)                                                     \
  {                                                                         \
    P0 = z16;                                                               \
    P1 = z16;                                                               \
    _Pragma("unroll") for (int m = 0; m < 4; ++m) {                         \
      P0 = __builtin_amdgcn_mfma_f32_32x32x16_bf16(A[m].v, Bf[0][m].v, P0, 0, 0, 0); \
      P1 = __builtin_amdgcn_mfma_f32_32x32x16_bf16(A[m].v, Bf[1][m].v, P1, 0, 0, 0); \
    }                                                                       \
  }

#define VQ_ARGMAX(P0, P1, CT)                                               \
  {                                                                         \
    const uint32_t ctor = (uint32_t)((CT) << 5) | (uint32_t)(half << 2);    \
    _Pragma("unroll") for (int r16 = 0; r16 < 16; ++r16) {                  \
      const uint32_t cr = (uint32_t)((r16 & 3) | ((r16 >> 2) << 3));        \
      uint32_t bits0 =                                                      \
          (__builtin_bit_cast(uint32_t, P0[r16]) & 0xFFFFFE00u) | (ctor | cr); \
      st[0] = fmaxf(st[0], __builtin_bit_cast(float, bits0));               \
      uint32_t bits1 =                                                      \
          (__builtin_bit_cast(uint32_t, P1[r16]) & 0xFFFFFE00u) | (ctor | cr); \
      st[1] = fmaxf(st[1], __builtin_bit_cast(float, bits1));               \
    }                                                                       \
  }

#define VQ_ACOPY() \
  { _Pragma("unroll") for (int m = 0; m < 4; ++m) A[m].u4 = An[m].u4; }

// ---- main: 512 blocks x 256 threads; wave = 64 rows (2 x 32-row C tiles),
// block = 256 rows/slab-iter x 2 iters. Codebook in LDS (XOR swizzle).
__global__ __launch_bounds__(256)
void vq_main(const float* __restrict__ zin, const uint32_t* __restrict__ cb_bf,
             const float* __restrict__ e2g, float* __restrict__ out) {
  // cbl dword addr for (code k, 16B chunk c): k*32 + ((c ^ (k&7)) << 2)
  __shared__ uint32_t cbl[16384];  // exactly 64 KB
  __shared__ unsigned short ks[2][256] __attribute__((aligned(16)));
  const int tid = threadIdx.x;
  const int wid = tid >> 6;
  const int lane = tid & 63;
  const int col = lane & 31;   // C col = z row within 32-tile
  const int half = lane >> 5;  // k-half for A/B frags
  const int xk = col & 7;      // XOR key for this lane's A codes
  const f32x16 z16 = {0, 0, 0, 0, 0, 0, 0, 0, 0, 0, 0, 0, 0, 0, 0, 0};

  // fill LDS codebook (swizzled), 16 x b128 per thread
  {
    const uint4* cb4 = (const uint4*)cb_bf;  // 4096 uint4
#pragma unroll
    for (int j = 0; j < 16; ++j) {
      int g = j * 256 + tid;
      int k = g >> 3, c = g & 7;
      *(uint4*)&cbl[k * 32 + ((c ^ (k & 7)) << 2)] = cb4[g];
    }
  }
  __syncthreads();

  float blk = 0.f;  // this wave's loss partial (all-lane dup after reduce)

#pragma unroll 1
  for (int it = 0; it < 2; ++it) {
    const int s = blockIdx.x * 2 + it;
    const int b = s >> 4;
    const int hw0 = (s & 15) << 8;
    const float* slab = zin + ((size_t)b << 18) + hw0;

    // P1: B-frags from global (dense lines) + z^2 partials
    ABu Bf[2][4];
    float z2[2];
#pragma unroll
    for (int rt = 0; rt < 2; ++rt) {
      const int r = wid * 64 + rt * 32 + col;
      float sacc = 0.f;
#pragma unroll
      for (int m = 0; m < 4; ++m) {
        const int d0 = m * 16 + half * 8;
#pragma unroll
        for (int p = 0; p < 4; ++p) {
          float va = slab[(size_t)(d0 + 2 * p) * 4096 + r];
          float vb = slab[(size_t)(d0 + 2 * p + 1) * 4096 + r];
          sacc += va * va + vb * vb;
          Bf[rt][m].w[p] = pack_bf16(va, vb);
        }
      }
      z2[rt] = sacc;
    }

    // P2: 16 code-tiles, software-pipelined (MFMA(ct) || ARGMAX(ct-1))
    ABu A[4], An[4];
#pragma unroll
    for (int m = 0; m < 4; ++m)
      A[m].u4 = *(const uint4*)&cbl[(col << 5) + (((2 * m + half) ^ xk) << 2)];
    float st[2] = {-3.4e38f, -3.4e38f};
    f32x16 a0, a1, b0, b1;
    // ct=0 into (a0,a1); prefetch A(1)
    VQ_LOAD_AN(1);
    VQ_MFMA(a0, a1);
    VQ_ACOPY();
#pragma unroll 1
    for (int i = 0; i < 7; ++i) {
      // ct = 2i+1 into b; argmax ct = 2i from a
      VQ_LOAD_AN(2 * i + 2);
      VQ_MFMA(b0, b1);
      VQ_ARGMAX(a0, a1, 2 * i);
      VQ_ACOPY();
      // ct = 2i+2 into a; argmax ct = 2i+1 from b
      VQ_LOAD_AN(2 * i + 3);
      VQ_MFMA(a0, a1);
      VQ_ARGMAX(b0, b1, 2 * i + 1);
      VQ_ACOPY();
    }
    // tail: ct=15 into b (A holds An(15)); argmax 14 then 15
    VQ_MFMA(b0, b1);
    VQ_ARGMAX(a0, a1, 14);
    VQ_ARGMAX(b0, b1, 15);

    // P3: combine halves, decode k, loss; stash codes for transposed P4'
    {
      float lsum = 0.f;
      int kk[2];
#pragma unroll
      for (int rt = 0; rt < 2; ++rt) {
        float mx = fmaxf(st[rt], __shfl_xor(st[rt], 32));
        float z2t = z2[rt] + __shfl_xor(z2[rt], 32);
        uint32_t mbits = __builtin_bit_cast(uint32_t, mx);
        kk[rt] = (int)(mbits & 511u);
        float dot = __builtin_bit_cast(float, mbits & 0xFFFFFE00u);
        lsum += z2t - 2.f * dot + e2g[kk[rt]];
      }
#pragma unroll
      for (int off = 1; off <= 16; off <<= 1) lsum += __shfl_xor(lsum, off);
      blk += lsum;
      if (half == 0) {
        ks[it][wid * 64 + col] = (unsigned short)kk[0];
        ks[it][wid * 64 + 32 + col] = (unsigned short)kk[1];
      }
    }
    __syncthreads();  // ks[it] visible to all waves (dbuf: no WAR race)

    // P4': plane-contiguous dequant stores (1KB wave-instrs)
    {
      float* oslab = out + ((size_t)b << 18) + hw0;
      const int r0 = (lane << 2);  // 0..252 step 4
      const uint2 kp = *(const uint2*)&ks[it][r0];
      int k4[4];
      k4[0] = (int)(kp.x & 0xFFFFu);
      k4[1] = (int)(kp.x >> 16);
      k4[2] = (int)(kp.y & 0xFFFFu);
      k4[3] = (int)(kp.y >> 16);
#pragma unroll
      for (int i = 0; i < 8; ++i) {
        const int d = wid * 16 + i * 2;      // even d; pair (d, d+1)
        const int c = (wid << 1) + (i >> 2); // d>>3
        const int jj = i & 3;                // (d>>1)&3
        uint32_t wv[4];
#pragma unroll
        for (int j = 0; j < 4; ++j)
          wv[j] = cbl[(k4[j] << 5) + (((c ^ (k4[j] & 7)) << 2) + jj)];
        float4 lo, hi;
        lo.x = __builtin_bit_cast(float, wv[0] << 16);
        lo.y = __builtin_bit_cast(float, wv[1] << 16);
        lo.z = __builtin_bit_cast(float, wv[2] << 16);
        lo.w = __builtin_bit_cast(float, wv[3] << 16);
        hi.x = __builtin_bit_cast(float, wv[0] & 0xFFFF0000u);
        hi.y = __builtin_bit_cast(float, wv[1] & 0xFFFF0000u);
        hi.z = __builtin_bit_cast(float, wv[2] & 0xFFFF0000u);
        hi.w = __builtin_bit_cast(float, wv[3] & 0xFFFF0000u);
        *(float4*)&oslab[(size_t)d * 4096 + r0] = lo;
        *(float4*)&oslab[(size_t)(d + 1) * 4096 + r0] = hi;
      }
    }
  }

  // block loss reduce: reuse cbl after all LDS codebook reads are done
  __syncthreads();
  if (lane == 0) ((float*)cbl)[wid] = blk;
  __syncthreads();
  if (tid == 0) {
    float t = ((float*)cbl)[0] + ((float*)cbl)[1] + ((float*)cbl)[2] + ((float*)cbl)[3];
    float sc = t * (1.0f / 16777216.0f);
    atomicAdd(out + 16777216, sc);
    atomicAdd(out + 16777217, 0.25f * sc);
  }
}

extern "C" void kernel_launch(void* const* d_in, const int* in_sizes, int n_in,
                              void* d_out, int out_size, void* d_ws, size_t ws_size,
                              hipStream_t stream) {
  const float* zin = (const float*)d_in[0];
  const float* cbf = (const float*)d_in[1];
  uint32_t* cb_bf = (uint32_t*)d_ws;                 // 64 KB bf16 codebook
  float* e2 = (float*)((char*)d_ws + 65536);         // 2 KB
  float* out = (float*)d_out;

  vq_prep<<<64, 256, 0, stream>>>(cbf, cb_bf, e2);
  vq_main<<<512, 256, 0, stream>>>(zin, cb_bf, e2, out);
}